// Round 5
// baseline (113.606 us; speedup 1.0000x reference)
//
#include <hip/hip_runtime.h>

typedef unsigned short ushort_t;
typedef __attribute__((ext_vector_type(8))) short short8;
typedef __attribute__((ext_vector_type(4))) float f32x4;

#define BM 128
#define BN 128

// ---------- helpers ----------

__device__ __forceinline__ ushort_t f32_to_bf16_rne(float x) {
    unsigned u = __builtin_bit_cast(unsigned, x);
    unsigned r = u + 0x7fffu + ((u >> 16) & 1u);
    return (ushort_t)(r >> 16);
}

__device__ __forceinline__ float bf16_to_f32(ushort_t h) {
    unsigned u = ((unsigned)h) << 16;
    return __builtin_bit_cast(float, u);
}

__device__ __forceinline__ void gload_lds16(const void* g, void* l) {
    __builtin_amdgcn_global_load_lds(
        (const __attribute__((address_space(1))) void*)g,
        (__attribute__((address_space(3))) void*)l,
        16, 0, 0);
}

// ---------- prep: fp32 X -> bf16 Xb (vectorized), sq from rounded values, zero out ----------
// D == 256 assumed: 16 rows/block, 16 threads/row, 16 elems/thread.

__global__ void krr_prep2(const float* __restrict__ X, ushort_t* __restrict__ Xb,
                          float* __restrict__ sq, float* __restrict__ out) {
    const int rl  = threadIdx.x >> 4;
    const int l   = threadIdx.x & 15;
    const int row = blockIdx.x * 16 + rl;
    const float*    src = X  + (size_t)row * 256 + l * 16;
    ushort_t*       dst = Xb + (size_t)row * 256 + l * 16;

    float s = 0.f;
    ushort_t tmp[16];
    #pragma unroll
    for (int i = 0; i < 16; ++i) {
        float x = src[i];
        ushort_t hb = f32_to_bf16_rne(x);
        tmp[i] = hb;
        float xf = bf16_to_f32(hb);
        s = fmaf(xf, xf, s);
    }
    *reinterpret_cast<short8*>(dst)     = *reinterpret_cast<short8*>(&tmp[0]);
    *reinterpret_cast<short8*>(dst + 8) = *reinterpret_cast<short8*>(&tmp[8]);

    s += __shfl_xor(s, 1, 16);
    s += __shfl_xor(s, 2, 16);
    s += __shfl_xor(s, 4, 16);
    s += __shfl_xor(s, 8, 16);
    if (l == 0) {
        sq[row]  = s;
        out[row] = 0.f;
    }
}

// ---------- symmetric fused kernel: full-K tile in LDS, quarter-K pipelined staging ----------
// LDS layout (elems): unit q in [q*16384, q*16384+16384): A-quarter [0,8192), B-quarter [8192,16384).
// Within a quarter: (r, slot 0..7) at (r*8+slot)*8; slot holds global k-chunk q*8 + (slot^(r&7)).

__global__ __launch_bounds__(256, 1) void krr_sym2(
    const ushort_t* __restrict__ Xb, const float* __restrict__ sq,
    const float* __restrict__ alpha, float* __restrict__ out,
    int N, int D)
{
    extern __shared__ __align__(16) ushort_t lds[];

    const int tid  = threadIdx.x;
    const int lane = tid & 63;
    const int w    = tid >> 6;          // 4 waves, 2x2
    const int wr   = (w >> 1) * 64;
    const int wc   = (w & 1) * 64;

    // bijective XCD-aware swizzle (m204 general form)
    const int nwg = gridDim.x;
    const int linear = blockIdx.x;
    const int q8 = nwg >> 3, r8 = nwg & 7;
    const int xcd = linear & 7, rest = linear >> 3;
    const int swz = (xcd < r8 ? xcd * (q8 + 1) : r8 * (q8 + 1) + (xcd - r8) * q8) + rest;

    // triangular decode: swz -> (ti, tj), ti <= tj
    const int T = N / BM;
    float Tf = (float)T + 0.5f;
    int ti = (int)(Tf - sqrtf(Tf * Tf - 2.0f * (float)swz));
    if (ti < 0) ti = 0;
    #define TRI_START(i) ((i) * T - ((i) * ((i) - 1)) / 2)
    while (TRI_START(ti + 1) <= swz) ++ti;
    while (TRI_START(ti) > swz) --ti;
    const int tj = ti + (swz - TRI_START(ti));
    #undef TRI_START
    const int rowBase = ti * BM;
    const int colBase = tj * BN;
    const bool offdiag = (ti != tj);
    const int bofs = offdiag ? 8192 : 0;   // B fragment base within unit

    f32x4 acc[4][4];
    #pragma unroll
    for (int m = 0; m < 4; ++m)
        #pragma unroll
        for (int n = 0; n < 4; ++n)
            acc[m][n] = (f32x4){0.f, 0.f, 0.f, 0.f};

    // ---- stage one 32KB unit (A-quarter + B-quarter); diag blocks skip B ----
    auto stage_unit = [&](int q) {
        #pragma unroll
        for (int it = 0; it < 4; ++it) {
            int idx = it * 256 + tid;          // 0..1023
            int r = idx >> 3, sl = idx & 7;
            int c8 = q * 8 + (sl ^ (r & 7));   // pre-swizzled global chunk
            gload_lds16(&Xb[(size_t)(rowBase + r) * D + c8 * 8],
                        &lds[q * 16384 + idx * 8]);
        }
        if (offdiag) {
            #pragma unroll
            for (int it = 0; it < 4; ++it) {
                int idx = it * 256 + tid;
                int r = idx >> 3, sl = idx & 7;
                int c8 = q * 8 + (sl ^ (r & 7));
                gload_lds16(&Xb[(size_t)(colBase + r) * D + c8 * 8],
                            &lds[q * 16384 + 8192 + idx * 8]);
            }
        }
    };

    // ---- compute phase p: k-steps 2p, 2p+1 (unit p resident) ----
    auto compute_phase = [&](int p) {
        #pragma unroll
        for (int kk = 0; kk < 2; ++kk) {
            const int ks  = p * 2 + kk;
            const int qb  = (ks >> 1) * 16384;
            const int c8w = (ks & 1) * 4 + (lane >> 4);   // 0..7
            short8 a[4], b[4];
            #pragma unroll
            for (int m = 0; m < 4; ++m) {
                int r = wr + m * 16 + (lane & 15);
                a[m] = *reinterpret_cast<const short8*>(
                    &lds[qb + (r * 8 + (c8w ^ (r & 7))) * 8]);
            }
            #pragma unroll
            for (int n = 0; n < 4; ++n) {
                int r = wc + n * 16 + (lane & 15);
                b[n] = *reinterpret_cast<const short8*>(
                    &lds[qb + bofs + (r * 8 + (c8w ^ (r & 7))) * 8]);
            }
            #pragma unroll
            for (int m = 0; m < 4; ++m)
                #pragma unroll
                for (int n = 0; n < 4; ++n)
                    acc[m][n] = __builtin_amdgcn_mfma_f32_16x16x32_bf16(
                        a[m], b[n], acc[m][n], 0, 0, 0);
        }
    };

    stage_unit(0);
    __syncthreads();                 // drains q0 only (exposed)
    stage_unit(1);
    compute_phase(0);
    __syncthreads();                 // drains q1 (hidden under phase 0)
    stage_unit(2);
    compute_phase(1);
    __syncthreads();                 // drains q2
    stage_unit(3);
    compute_phase(2);
    __syncthreads();                 // drains q3
    compute_phase(3);

    // ---- fused symmetric epilogue ----
    float sqc[4], alc[4];
    #pragma unroll
    for (int n = 0; n < 4; ++n) {
        int c = colBase + wc + n * 16 + (lane & 15);
        sqc[n] = sq[c];
        alc[n] = alpha[c];
    }
    float csum[4] = {0.f, 0.f, 0.f, 0.f};
    const int g = lane >> 4;
    #pragma unroll
    for (int m = 0; m < 4; ++m) {
        int r0 = rowBase + wr + m * 16 + g * 4;
        #pragma unroll
        for (int reg = 0; reg < 4; ++reg) {
            float sqr = sq[r0 + reg];
            float ar  = alpha[r0 + reg];
            float s = 0.f;
            #pragma unroll
            for (int n = 0; n < 4; ++n) {
                float d2 = sqr + sqc[n] - 2.0f * acc[m][n][reg];
                d2 = fmaxf(d2, 0.f);
                float k = __expf(-d2);
                s += k * alc[n];
                csum[n] = fmaf(k, ar, csum[n]);
            }
            s += __shfl_xor(s, 1, 16);
            s += __shfl_xor(s, 2, 16);
            s += __shfl_xor(s, 4, 16);
            s += __shfl_xor(s, 8, 16);
            if ((lane & 15) == 0) atomicAdd(&out[r0 + reg], s);
        }
    }
    if (offdiag) {
        #pragma unroll
        for (int n = 0; n < 4; ++n) {
            csum[n] += __shfl_xor(csum[n], 16, 64);
            csum[n] += __shfl_xor(csum[n], 32, 64);
            if (g == 0)
                atomicAdd(&out[colBase + wc + n * 16 + (lane & 15)], csum[n]);
        }
    }
}

// ---------- fallback: honest fp32, slow ----------

__global__ void krr_naive(const float* __restrict__ X, const float* __restrict__ alpha,
                          float* __restrict__ out, int N, int D) {
    __shared__ float xi[256];
    const int i = blockIdx.x;
    const int t = threadIdx.x;
    for (int k = t; k < D; k += blockDim.x) xi[k] = X[(size_t)i * D + k];
    __syncthreads();
    float s = 0.f;
    for (int j = t; j < N; j += blockDim.x) {
        float d2 = 0.f;
        const float* xj = &X[(size_t)j * D];
        for (int k = 0; k < D; ++k) {
            float d = xi[k] - xj[k];
            d2 = fmaf(d, d, d2);
        }
        s += __expf(-fmaxf(d2, 0.f)) * alpha[j];
    }
    #pragma unroll
    for (int off = 32; off > 0; off >>= 1) s += __shfl_xor(s, off, 64);
    __shared__ float red[4];
    const int lane = t & 63, w = t >> 6;
    if (lane == 0) red[w] = s;
    __syncthreads();
    if (t == 0) out[i] = red[0] + red[1] + red[2] + red[3];
}

// ---------- launch ----------

extern "C" void kernel_launch(void* const* d_in, const int* in_sizes, int n_in,
                              void* d_out, int out_size, void* d_ws, size_t ws_size,
                              hipStream_t stream) {
    const float* X     = (const float*)d_in[0];
    const float* alpha = (const float*)d_in[1];
    float* out = (float*)d_out;

    const int N = in_sizes[1];           // 8192
    const int D = in_sizes[0] / N;       // 256

    size_t xb_bytes = (size_t)N * D * sizeof(ushort_t);
    size_t need     = xb_bytes + (size_t)N * sizeof(float);

    bool shapes_ok = (D == 256) && (N % BM) == 0 && (N % 16) == 0 && (N == out_size);

    hipError_t e = hipFuncSetAttribute(
        reinterpret_cast<const void*>(krr_sym2),
        hipFuncAttributeMaxDynamicSharedMemorySize, 131072);

    if (ws_size >= need && shapes_ok && e == hipSuccess) {
        ushort_t* Xb = (ushort_t*)d_ws;
        float*    sq = (float*)((char*)d_ws + xb_bytes);
        krr_prep2<<<N / 16, 256, 0, stream>>>(X, Xb, sq, out);
        const int T = N / BM;
        const int ntiles = T * (T + 1) / 2;   // 2080 for N=8192
        krr_sym2<<<ntiles, 256, 131072, stream>>>(Xb, sq, alpha, out, N, D);
    } else {
        hipMemsetAsync(d_out, 0, (size_t)out_size * sizeof(float), stream);
        krr_naive<<<N, 256, 0, stream>>>(X, alpha, out, N, D);
    }
}

// Round 7
// 62.099 us; speedup vs baseline: 1.8294x; 1.8294x over previous
//
#include <hip/hip_runtime.h>

typedef unsigned char u8;
typedef __attribute__((ext_vector_type(4))) float f32x4;
typedef __attribute__((ext_vector_type(4))) int i32x4;

// ---------- helpers ----------

__device__ __forceinline__ void gload_lds16(const void* g, void* l) {
    __builtin_amdgcn_global_load_lds(
        (const __attribute__((address_space(1))) void*)g,
        (__attribute__((address_space(3))) void*)l,
        16, 0, 0);
}

// ---------- prep: fp32 X -> fp8 e4m3 Xb (HW RNE cvt), sq from rounded values, zero out ----------
// D == 256: 16 rows/block, 16 threads/row, 16 elems/thread -> one 16B store.

__global__ void krr_prep8(const float* __restrict__ X, u8* __restrict__ Xb,
                          float* __restrict__ sq, float* __restrict__ out) {
    const int rl  = threadIdx.x >> 4;
    const int l   = threadIdx.x & 15;
    const int row = blockIdx.x * 16 + rl;
    const float* src = X + (size_t)row * 256 + l * 16;

    float s = 0.f;
    int wv[4];
    #pragma unroll
    for (int c = 0; c < 4; ++c) {
        int pk = __builtin_amdgcn_cvt_pk_fp8_f32(src[c*4+0], src[c*4+1], 0, false);
        pk     = __builtin_amdgcn_cvt_pk_fp8_f32(src[c*4+2], src[c*4+3], pk, true);
        wv[c] = pk;
        float x0 = __builtin_amdgcn_cvt_f32_fp8(pk, 0);
        float x1 = __builtin_amdgcn_cvt_f32_fp8(pk, 1);
        float x2 = __builtin_amdgcn_cvt_f32_fp8(pk, 2);
        float x3 = __builtin_amdgcn_cvt_f32_fp8(pk, 3);
        s = fmaf(x0, x0, s);
        s = fmaf(x1, x1, s);
        s = fmaf(x2, x2, s);
        s = fmaf(x3, x3, s);
    }
    *reinterpret_cast<i32x4*>(Xb + (size_t)row * 256 + l * 16) =
        (i32x4){wv[0], wv[1], wv[2], wv[3]};

    s += __shfl_xor(s, 1, 16);
    s += __shfl_xor(s, 2, 16);
    s += __shfl_xor(s, 4, 16);
    s += __shfl_xor(s, 8, 16);
    if (l == 0) {
        sq[row]  = s;
        out[row] = 0.f;
    }
}

// ---------- symmetric fused kernel: fp8 MFMA, dbuf 2-phase pipeline, multi-tile blocks ----------
// LDS: buf{0,1} x { A[128 rows x 64 B], B[128 x 64 B] } = 32 KiB.
// Row = 64 B = four 16B chunks; chunk p stored from global chunk p^((r>>1)&3) (involution).

__global__ __launch_bounds__(256, 4) void krr_sym8(
    const u8* __restrict__ Xb, const float* __restrict__ sq,
    const float* __restrict__ alpha, float* __restrict__ out,
    int N, int ntiles, int nblk)
{
    __shared__ __align__(16) u8 lds[32768];

    const int tid  = threadIdx.x;
    const int lane = tid & 63;
    const int w    = tid >> 6;          // 4 waves, 2x2
    const int wr   = (w >> 1) * 64;
    const int wc   = (w & 1) * 64;
    const int T    = N >> 7;

    // XCD-chunked contiguous tile range for this block
    const int xcd = blockIdx.x & 7;
    const int wi  = blockIdx.x >> 3;
    const int TPX = ntiles >> 3;
    const int WB  = nblk >> 3;
    const int lo  = xcd * TPX + (int)(((long)wi * TPX) / WB);
    const int hi  = xcd * TPX + (int)(((long)(wi + 1) * TPX) / WB);
    const int s_end = (hi - lo) * 4;
    if (s_end <= 0) return;

    const float Tf = (float)T + 0.5f;
    auto decode = [&](int t, int& rb, int& cb, bool& od) {
        int ti = (int)(Tf - sqrtf(fmaxf(Tf * Tf - 2.0f * (float)t, 0.f)));
        if (ti < 0) ti = 0;
        if (ti > T - 1) ti = T - 1;
        while ((ti + 1) * T - ((ti + 1) * ti) / 2 <= t) ++ti;
        while (ti * T - (ti * (ti - 1)) / 2 > t) --ti;
        int tj = ti + (t - (ti * T - (ti * (ti - 1)) / 2));
        rb = ti << 7; cb = tj << 7; od = (ti != tj);
    };

    auto stage = [&](int rb, int cb, int kt, int buf) {
        u8* A = &lds[buf * 16384];
        u8* B = A + 8192;
        #pragma unroll
        for (int it = 0; it < 2; ++it) {
            int idx = it * 256 + tid;          // 0..511 (16B chunks per panel)
            int r = idx >> 2, p = idx & 3;
            int px = p ^ ((r >> 1) & 3);       // pre-swizzled global chunk
            gload_lds16(&Xb[(size_t)(rb + r) * 256 + kt * 64 + px * 16], &A[idx * 16]);
            gload_lds16(&Xb[(size_t)(cb + r) * 256 + kt * 64 + px * 16], &B[idx * 16]);
        }
    };

    f32x4 acc[4][4];
    #pragma unroll
    for (int m = 0; m < 4; ++m)
        #pragma unroll
        for (int n = 0; n < 4; ++n)
            acc[m][n] = (f32x4){0.f, 0.f, 0.f, 0.f};

    const int cg = lane >> 4;        // 0..3: k-chunk group
    const int hh = cg & 1;           // 8B half within 16B chunk

    auto compute = [&](int buf) {
        const u8* A = &lds[buf * 16384];
        const u8* B = A + 8192;
        #pragma unroll
        for (int ks = 0; ks < 2; ++ks) {
            const int g = ks * 2 + (cg >> 1);     // 16B chunk holding this 8B k-group
            long a[4], b[4];
            #pragma unroll
            for (int m = 0; m < 4; ++m) {
                int r = wr + m * 16 + (lane & 15);
                a[m] = *reinterpret_cast<const long*>(
                    &A[r * 64 + ((g ^ ((r >> 1) & 3)) * 16) + hh * 8]);
            }
            #pragma unroll
            for (int n = 0; n < 4; ++n) {
                int r = wc + n * 16 + (lane & 15);
                b[n] = *reinterpret_cast<const long*>(
                    &B[r * 64 + ((g ^ ((r >> 1) & 3)) * 16) + hh * 8]);
            }
            #pragma unroll
            for (int m = 0; m < 4; ++m)
                #pragma unroll
                for (int n = 0; n < 4; ++n)
                    acc[m][n] = __builtin_amdgcn_mfma_f32_16x16x32_fp8_fp8(
                        a[m], b[n], acc[m][n], 0, 0, 0);
        }
    };

    const int g4 = lane >> 4;
    auto epilogue = [&](int rb, int cb, bool od) {
        float sqc[4], alc[4];
        #pragma unroll
        for (int n = 0; n < 4; ++n) {
            int c = cb + wc + n * 16 + (lane & 15);
            sqc[n] = sq[c];
            alc[n] = alpha[c];
        }
        float csum[4] = {0.f, 0.f, 0.f, 0.f};
        #pragma unroll
        for (int m = 0; m < 4; ++m) {
            int r0 = rb + wr + m * 16 + g4 * 4;
            #pragma unroll
            for (int reg = 0; reg < 4; ++reg) {
                float sqr = sq[r0 + reg];
                float ar  = alpha[r0 + reg];
                float s = 0.f;
                #pragma unroll
                for (int n = 0; n < 4; ++n) {
                    float d2 = sqr + sqc[n] - 2.0f * acc[m][n][reg];
                    d2 = fmaxf(d2, 0.f);
                    float k = __expf(-d2);
                    s += k * alc[n];
                    csum[n] = fmaf(k, ar, csum[n]);
                }
                s += __shfl_xor(s, 1, 16);
                s += __shfl_xor(s, 2, 16);
                s += __shfl_xor(s, 4, 16);
                s += __shfl_xor(s, 8, 16);
                if ((lane & 15) == 0) atomicAdd(&out[r0 + reg], s);
            }
        }
        if (od) {
            #pragma unroll
            for (int n = 0; n < 4; ++n) {
                csum[n] += __shfl_xor(csum[n], 16, 64);
                csum[n] += __shfl_xor(csum[n], 32, 64);
                if (g4 == 0)
                    atomicAdd(&out[cb + wc + n * 16 + (lane & 15)], csum[n]);
            }
        }
        #pragma unroll
        for (int m = 0; m < 4; ++m)
            #pragma unroll
            for (int n = 0; n < 4; ++n)
                acc[m][n] = (f32x4){0.f, 0.f, 0.f, 0.f};
    };

    // ---- pipeline: stage(0); sync; loop { stage(next,buf^1); compute(buf); [epi]; sync } ----
    int rbN, cbN; bool odN;
    decode(lo, rbN, cbN, odN);
    int rbC = rbN, cbC = cbN; bool odC = odN;
    stage(rbN, cbN, 0, 0);
    __syncthreads();

    int buf = 0;
    for (int s = 0; s < s_end; ++s) {
        const int kt = s & 3;
        if (s + 1 < s_end) {
            const int nk = (s + 1) & 3;
            if (nk == 0) decode(lo + ((s + 1) >> 2), rbN, cbN, odN);
            stage(rbN, cbN, nk, buf ^ 1);
        }
        compute(buf);
        if (kt == 3) {
            epilogue(rbC, cbC, odC);     // overlaps next tile's first stage
            rbC = rbN; cbC = cbN; odC = odN;
        }
        __syncthreads();
        buf ^= 1;
    }
}

// ---------- fallback: honest fp32, slow ----------

__global__ void krr_naive(const float* __restrict__ X, const float* __restrict__ alpha,
                          float* __restrict__ out, int N, int D) {
    __shared__ float xi[256];
    const int i = blockIdx.x;
    const int t = threadIdx.x;
    for (int k = t; k < D; k += blockDim.x) xi[k] = X[(size_t)i * D + k];
    __syncthreads();
    float s = 0.f;
    for (int j = t; j < N; j += blockDim.x) {
        float d2 = 0.f;
        const float* xj = &X[(size_t)j * D];
        for (int k = 0; k < D; ++k) {
            float d = xi[k] - xj[k];
            d2 = fmaf(d, d, d2);
        }
        s += __expf(-fmaxf(d2, 0.f)) * alpha[j];
    }
    #pragma unroll
    for (int off = 32; off > 0; off >>= 1) s += __shfl_xor(s, off, 64);
    __shared__ float red[4];
    const int lane = t & 63, w = t >> 6;
    if (lane == 0) red[w] = s;
    __syncthreads();
    if (t == 0) out[i] = red[0] + red[1] + red[2] + red[3];
}

// ---------- launch ----------

extern "C" void kernel_launch(void* const* d_in, const int* in_sizes, int n_in,
                              void* d_out, int out_size, void* d_ws, size_t ws_size,
                              hipStream_t stream) {
    const float* X     = (const float*)d_in[0];
    const float* alpha = (const float*)d_in[1];
    float* out = (float*)d_out;

    const int N = in_sizes[1];           // 8192
    const int D = in_sizes[0] / N;       // 256

    size_t xb_bytes = (size_t)N * D;     // fp8: 1 B/elem
    size_t need     = xb_bytes + (size_t)N * sizeof(float);

    const int T = N >> 7;
    const int ntiles = T * (T + 1) / 2;  // 2080 for N=8192

    bool shapes_ok = (D == 256) && (N % 128) == 0 && (ntiles % 8) == 0 && (N == out_size);

    if (ws_size >= need && shapes_ok) {
        u8*    Xb = (u8*)d_ws;
        float* sq = (float*)((char*)d_ws + xb_bytes);
        krr_prep8<<<N / 16, 256, 0, stream>>>(X, Xb, sq, out);
        int nblk = ntiles < 1040 ? ntiles : 1040;   // both % 8 == 0
        krr_sym8<<<nblk, 256, 0, stream>>>(Xb, sq, alpha, out, N, ntiles, nblk);
    } else {
        (void)hipMemsetAsync(d_out, 0, (size_t)out_size * sizeof(float), stream);
        krr_naive<<<N, 256, 0, stream>>>(X, alpha, out, N, D);
    }
}